// Round 1
// baseline (554.014 us; speedup 1.0000x reference)
//
#include <hip/hip_runtime.h>
#include <cstdint>
#include <cstddef>

// Problem constants (match reference)
constexpr int CB = 2;      // batch
constexpr int CS = 2048;   // seq
constexpr int CD = 1024;   // model dim
constexpr int CH = 16;     // heads
constexpr int CDK = 64;    // head dim
constexpr float NEGV = -1000000000.0f;

typedef __bf16 bf16x8 __attribute__((ext_vector_type(8)));
typedef float f32x4 __attribute__((ext_vector_type(4)));
typedef unsigned short u16x8 __attribute__((ext_vector_type(8)));
typedef unsigned short u16x4 __attribute__((ext_vector_type(4)));

static __device__ __forceinline__ unsigned short f2bf(float x) {
  unsigned int u = __float_as_uint(x);
  u += 0x7fffu + ((u >> 16) & 1u);   // round-to-nearest-even
  return (unsigned short)(u >> 16);
}
static __device__ __forceinline__ bf16x8 bc8(u16x8 u) {
  return __builtin_bit_cast(bf16x8, u);
}
static __device__ __forceinline__ f32x4 mfma16(bf16x8 a, bf16x8 b, f32x4 c) {
  return __builtin_amdgcn_mfma_f32_16x16x32_bf16(a, b, c, 0, 0, 0);
}

// ---------------------------------------------------------------- cvt f32->bf16
__global__ __launch_bounds__(256) void cvt_f32_bf16(const float* __restrict__ in,
                                                    unsigned short* __restrict__ out,
                                                    int n4) {
  int i = blockIdx.x * 256 + threadIdx.x;
  const int stride = gridDim.x * 256;
  for (; i < n4; i += stride) {
    float4 v = reinterpret_cast<const float4*>(in)[i];
    u16x4 o;
    o[0] = f2bf(v.x); o[1] = f2bf(v.y); o[2] = f2bf(v.z); o[3] = f2bf(v.w);
    reinterpret_cast<u16x4*>(out)[i] = o;
  }
}

// ---------------------------------------------------------------- GEMM: C = X @ W^T + bias
// X[M,K] bf16 row-major, W[N,K] bf16 row-major (NT gemm, both K-contiguous).
// MODE 0: write bf16 head-split   out[(b*H+h)*S+s)*DK+dk]   (q,k)
// MODE 1: write bf16 head-split-T out[((b*H+h)*DK+dk)*S+s]  (v^T)
// MODE 2: write f32 row-major     out[row*N+col]            (fc output)
constexpr int GBM = 128, GBN = 128, GBK = 32, GLD = 40;

template <int MODE>
__global__ __launch_bounds__(256) void gemm_nt(const unsigned short* __restrict__ X,
                                               const unsigned short* __restrict__ Wt,
                                               const float* __restrict__ bias,
                                               void* __restrict__ outp,
                                               int M, int N, int K) {
  __shared__ unsigned short lA[GBM * GLD];
  __shared__ unsigned short lB[GBN * GLD];
  const int tid = threadIdx.x, lane = tid & 63, wid = tid >> 6;
  const int mbase = blockIdx.y * GBM, nbase = blockIdx.x * GBN;
  const int wm = (wid & 1) * 64, wn = (wid >> 1) * 64;
  const int trow = tid >> 2, tcol = (tid & 3) * 8;

  f32x4 acc[4][4] = {};

  for (int k0 = 0; k0 < K; k0 += GBK) {
    __syncthreads();
    *reinterpret_cast<u16x8*>(&lA[trow * GLD + tcol]) =
        *reinterpret_cast<const u16x8*>(&X[(size_t)(mbase + trow) * K + k0 + tcol]);
    *reinterpret_cast<u16x8*>(&lA[(trow + 64) * GLD + tcol]) =
        *reinterpret_cast<const u16x8*>(&X[(size_t)(mbase + trow + 64) * K + k0 + tcol]);
    *reinterpret_cast<u16x8*>(&lB[trow * GLD + tcol]) =
        *reinterpret_cast<const u16x8*>(&Wt[(size_t)(nbase + trow) * K + k0 + tcol]);
    *reinterpret_cast<u16x8*>(&lB[(trow + 64) * GLD + tcol]) =
        *reinterpret_cast<const u16x8*>(&Wt[(size_t)(nbase + trow + 64) * K + k0 + tcol]);
    __syncthreads();

    bf16x8 af[4], bfv[4];
#pragma unroll
    for (int i = 0; i < 4; ++i)
      af[i] = bc8(*reinterpret_cast<const u16x8*>(
          &lA[(wm + i * 16 + (lane & 15)) * GLD + (lane >> 4) * 8]));
#pragma unroll
    for (int j = 0; j < 4; ++j)
      bfv[j] = bc8(*reinterpret_cast<const u16x8*>(
          &lB[(wn + j * 16 + (lane & 15)) * GLD + (lane >> 4) * 8]));
#pragma unroll
    for (int i = 0; i < 4; ++i)
#pragma unroll
      for (int j = 0; j < 4; ++j)
        acc[i][j] = mfma16(af[i], bfv[j], acc[i][j]);
  }

#pragma unroll
  for (int j = 0; j < 4; ++j) {
    const int colb = nbase + wn + j * 16 + (lane & 15);
    const float bv = bias[colb];
#pragma unroll
    for (int i = 0; i < 4; ++i) {
#pragma unroll
      for (int r = 0; r < 4; ++r) {
        const int rowb = mbase + wm + i * 16 + (lane >> 4) * 4 + r;
        const float v = acc[i][j][r] + bv;
        if constexpr (MODE == 2) {
          reinterpret_cast<float*>(outp)[(size_t)rowb * N + colb] = v;
        } else {
          const int bb = rowb >> 11, sr = rowb & (CS - 1);
          const int hh = colb >> 6, dk = colb & (CDK - 1);
          if constexpr (MODE == 0)
            reinterpret_cast<unsigned short*>(outp)[(((size_t)bb * CH + hh) * CS + sr) * CDK + dk] =
                f2bf(v);
          else
            reinterpret_cast<unsigned short*>(outp)[(((size_t)bb * CH + hh) * CDK + dk) * CS + sr] =
                f2bf(v);
        }
      }
    }
  }
}

// ---------------------------------------------------------------- fused attention
// One block (4 waves) per (b, h, 64-query tile). Wave w owns queries qbase+w*16..+15.
// Pass 1: exact row max m and denom l (online, over 32 key-tiles of 64).
// Pass 2: recompute scores, w = exp(s-m)/l, write attn_weights (coalesced via LDS
// transpose), accumulate O = w @ V from v^T (k-contiguous B-frags).
constexpr int KLD = 72;  // K-tile LDS row stride (bf16), pad vs bank conflicts
constexpr int WLD = 68;  // w-tile LDS row stride (f32)

__global__ __launch_bounds__(256) void attn_fused(const unsigned short* __restrict__ qh,
                                                  const unsigned short* __restrict__ kh,
                                                  const unsigned short* __restrict__ vT,
                                                  const unsigned char* __restrict__ mask,
                                                  float* __restrict__ attnw,
                                                  unsigned short* __restrict__ attn_pre) {
  __shared__ unsigned short lK[64 * KLD];
  __shared__ float lW[4][16 * WLD];
  __shared__ int sflag[32 * 4];

  const int tid = threadIdx.x, lane = tid & 63, wid = tid >> 6;
  const int qt = blockIdx.x, hh = blockIdx.y, b = blockIdx.z;
  const int bh = b * CH + hh;
  const int qbase = qt * 64;
  const int qw = qbase + wid * 16;
  const float scale = 0.125f;  // 1/sqrt(64)

  // q fragments (A): row = lane&15 (query), k = (lane>>4)*8.. per 32-chunk
  const unsigned short* qp = qh + ((size_t)bh * CS + qw + (lane & 15)) * CDK + (lane >> 4) * 8;
  const bf16x8 aq0 = bc8(*reinterpret_cast<const u16x8*>(qp));
  const bf16x8 aq1 = bc8(*reinterpret_cast<const u16x8*>(qp + 32));

  float m_r[4], l_r[4];
#pragma unroll
  for (int r = 0; r < 4; ++r) { m_r[r] = -1e30f; l_r[r] = 0.f; }

  const int krow = tid >> 3, kc8 = (tid & 7) * 8;      // K-tile staging map (2 rows/thread)
  const int mrow = tid >> 2, mc16 = (tid & 3) * 16;    // mask staging map
  const size_t krow0 = (size_t)bh * CS;

  // ---------------- pass 1: m, l
  for (int kt = 0; kt < CS / 64; ++kt) {
    __syncthreads();
    *reinterpret_cast<u16x8*>(&lK[krow * KLD + kc8]) =
        *reinterpret_cast<const u16x8*>(&kh[(krow0 + kt * 64 + krow) * CDK + kc8]);
    *reinterpret_cast<u16x8*>(&lK[(krow + 32) * KLD + kc8]) =
        *reinterpret_cast<const u16x8*>(&kh[(krow0 + kt * 64 + krow + 32) * CDK + kc8]);
    const uint4 mv = *reinterpret_cast<const uint4*>(
        &mask[((size_t)b * CS + qbase + mrow) * CS + kt * 64 + mc16]);
    const int nz = (mv.x | mv.y | mv.z | mv.w) != 0;
    const unsigned long long bal = __ballot(nz);
    if (lane == 0) sflag[kt * 4 + wid] = (bal != 0ull) ? 1 : 0;
    __syncthreads();
    const int dirty = sflag[kt * 4] | sflag[kt * 4 + 1] | sflag[kt * 4 + 2] | sflag[kt * 4 + 3];

    f32x4 sf[4];
#pragma unroll
    for (int g = 0; g < 4; ++g) {
      const bf16x8 kb0 = bc8(*reinterpret_cast<const u16x8*>(
          &lK[(g * 16 + (lane & 15)) * KLD + (lane >> 4) * 8]));
      const bf16x8 kb1 = bc8(*reinterpret_cast<const u16x8*>(
          &lK[(g * 16 + (lane & 15)) * KLD + 32 + (lane >> 4) * 8]));
      f32x4 a = {0.f, 0.f, 0.f, 0.f};
      a = mfma16(aq0, kb0, a);
      a = mfma16(aq1, kb1, a);
      sf[g] = a;
    }
    if (dirty) {
#pragma unroll
      for (int g = 0; g < 4; ++g)
#pragma unroll
        for (int r = 0; r < 4; ++r) {
          const unsigned char mb =
              mask[((size_t)b * CS + qw + (lane >> 4) * 4 + r) * CS + kt * 64 + g * 16 + (lane & 15)];
          sf[g][r] = mb ? NEGV : sf[g][r] * scale;
        }
    } else {
#pragma unroll
      for (int g = 0; g < 4; ++g)
#pragma unroll
        for (int r = 0; r < 4; ++r) sf[g][r] *= scale;
    }
#pragma unroll
    for (int r = 0; r < 4; ++r) {
      float mx = fmaxf(fmaxf(sf[0][r], sf[1][r]), fmaxf(sf[2][r], sf[3][r]));
      mx = fmaxf(mx, __shfl_xor(mx, 1));
      mx = fmaxf(mx, __shfl_xor(mx, 2));
      mx = fmaxf(mx, __shfl_xor(mx, 4));
      mx = fmaxf(mx, __shfl_xor(mx, 8));
      const float mn = fmaxf(m_r[r], mx);
      float sm = __expf(sf[0][r] - mn) + __expf(sf[1][r] - mn) +
                 __expf(sf[2][r] - mn) + __expf(sf[3][r] - mn);
      sm += __shfl_xor(sm, 1);
      sm += __shfl_xor(sm, 2);
      sm += __shfl_xor(sm, 4);
      sm += __shfl_xor(sm, 8);
      l_r[r] = l_r[r] * __expf(m_r[r] - mn) + sm;
      m_r[r] = mn;
    }
  }

  float linv[4];
#pragma unroll
  for (int r = 0; r < 4; ++r) linv[r] = 1.0f / l_r[r];

  // ---------------- pass 2: weights write + PV
  f32x4 o[4] = {};
  for (int kt = 0; kt < CS / 64; ++kt) {
    __syncthreads();
    *reinterpret_cast<u16x8*>(&lK[krow * KLD + kc8]) =
        *reinterpret_cast<const u16x8*>(&kh[(krow0 + kt * 64 + krow) * CDK + kc8]);
    *reinterpret_cast<u16x8*>(&lK[(krow + 32) * KLD + kc8]) =
        *reinterpret_cast<const u16x8*>(&kh[(krow0 + kt * 64 + krow + 32) * CDK + kc8]);
    __syncthreads();
    const int dirty = sflag[kt * 4] | sflag[kt * 4 + 1] | sflag[kt * 4 + 2] | sflag[kt * 4 + 3];

    f32x4 sf[4];
#pragma unroll
    for (int g = 0; g < 4; ++g) {
      const bf16x8 kb0 = bc8(*reinterpret_cast<const u16x8*>(
          &lK[(g * 16 + (lane & 15)) * KLD + (lane >> 4) * 8]));
      const bf16x8 kb1 = bc8(*reinterpret_cast<const u16x8*>(
          &lK[(g * 16 + (lane & 15)) * KLD + 32 + (lane >> 4) * 8]));
      f32x4 a = {0.f, 0.f, 0.f, 0.f};
      a = mfma16(aq0, kb0, a);
      a = mfma16(aq1, kb1, a);
      sf[g] = a;
    }
    if (dirty) {
#pragma unroll
      for (int g = 0; g < 4; ++g)
#pragma unroll
        for (int r = 0; r < 4; ++r) {
          const unsigned char mb =
              mask[((size_t)b * CS + qw + (lane >> 4) * 4 + r) * CS + kt * 64 + g * 16 + (lane & 15)];
          sf[g][r] = mb ? NEGV : sf[g][r] * scale;
        }
    } else {
#pragma unroll
      for (int g = 0; g < 4; ++g)
#pragma unroll
        for (int r = 0; r < 4; ++r) sf[g][r] *= scale;
    }
    // final normalized weights
#pragma unroll
    for (int g = 0; g < 4; ++g)
#pragma unroll
      for (int r = 0; r < 4; ++r) sf[g][r] = __expf(sf[g][r] - m_r[r]) * linv[r];

    // per-wave LDS transpose: [query 0..15][key 0..63]
#pragma unroll
    for (int g = 0; g < 4; ++g)
#pragma unroll
      for (int r = 0; r < 4; ++r)
        lW[wid][((lane >> 4) * 4 + r) * WLD + g * 16 + (lane & 15)] = sf[g][r];

    // coalesced f32 weight store: 4 rows x 256B per instruction
#pragma unroll
    for (int it = 0; it < 4; ++it) {
      const int row = it * 4 + (lane >> 4);
      const f32x4 wv = *reinterpret_cast<const f32x4*>(&lW[wid][row * WLD + (lane & 15) * 4]);
      *reinterpret_cast<f32x4*>(
          &attnw[((size_t)bh * CS + qw + row) * CS + kt * 64 + (lane & 15) * 4]) = wv;
    }

    // PV A-frags from transposed tile: row = lane&15 (query), keys contiguous
    bf16x8 wa[2];
#pragma unroll
    for (int c = 0; c < 2; ++c) {
      const f32x4 t0 = *reinterpret_cast<const f32x4*>(
          &lW[wid][(lane & 15) * WLD + c * 32 + (lane >> 4) * 8]);
      const f32x4 t1 = *reinterpret_cast<const f32x4*>(
          &lW[wid][(lane & 15) * WLD + c * 32 + (lane >> 4) * 8 + 4]);
      u16x8 u;
#pragma unroll
      for (int z = 0; z < 4; ++z) { u[z] = f2bf(t0[z]); u[z + 4] = f2bf(t1[z]); }
      wa[c] = bc8(u);
    }
#pragma unroll
    for (int g = 0; g < 4; ++g) {
      const unsigned short* vp =
          vT + ((size_t)bh * CDK + g * 16 + (lane & 15)) * CS + kt * 64 + (lane >> 4) * 8;
      o[g] = mfma16(wa[0], bc8(*reinterpret_cast<const u16x8*>(vp)), o[g]);
      o[g] = mfma16(wa[1], bc8(*reinterpret_cast<const u16x8*>(vp + 32)), o[g]);
    }
  }

  // epilogue: attn_pre [b][s][h][dk] bf16 (fc GEMM input layout)
#pragma unroll
  for (int g = 0; g < 4; ++g)
#pragma unroll
    for (int r = 0; r < 4; ++r) {
      const int q = qw + (lane >> 4) * 4 + r;
      attn_pre[(((size_t)b * CS + q) * CH + hh) * CDK + g * 16 + (lane & 15)] = f2bf(o[g][r]);
    }
}

// ---------------------------------------------------------------- launch
extern "C" void kernel_launch(void* const* d_in, const int* in_sizes, int n_in,
                              void* d_out, int out_size, void* d_ws, size_t ws_size,
                              hipStream_t stream) {
  (void)in_sizes; (void)n_in; (void)out_size; (void)ws_size;

  const float* Qf = (const float*)d_in[0];
  const float* Kf = (const float*)d_in[1];
  const float* Vf = (const float*)d_in[2];
  const unsigned char* mask = (const unsigned char*)d_in[3];
  const float* WQw = (const float*)d_in[4];
  const float* WQb = (const float*)d_in[5];
  const float* WKw = (const float*)d_in[6];
  const float* WKb = (const float*)d_in[7];
  const float* WVw = (const float*)d_in[8];
  const float* WVb = (const float*)d_in[9];
  const float* fcw = (const float*)d_in[10];
  const float* fcb = (const float*)d_in[11];

  float* out0 = (float*)d_out;
  float* attnw = out0 + (size_t)CB * CS * CD;  // attn_weights region

  // workspace layout (58.7 MB total)
  char* w = (char*)d_ws;
  unsigned short* Qb = (unsigned short*)(w);
  unsigned short* Kb = (unsigned short*)(w + 8388608);
  unsigned short* Vb = (unsigned short*)(w + 2 * 8388608);
  unsigned short* Wqb = (unsigned short*)(w + 3 * 8388608);
  unsigned short* Wkb = Wqb + 1048576;
  unsigned short* Wvb = Wkb + 1048576;
  unsigned short* Wfb = Wvb + 1048576;
  unsigned short* qhp = (unsigned short*)(w + 3 * 8388608 + 4 * 2097152);
  unsigned short* khp = qhp + 4194304;
  unsigned short* vTp = khp + 4194304;
  unsigned short* apre = Qb;  // alias: Qb dead after q projection

  const int NELEM4 = (CB * CS * CD) / 4;  // 1048576
  const int WELEM4 = (CD * CD) / 4;       // 262144

  cvt_f32_bf16<<<2048, 256, 0, stream>>>(Qf, Qb, NELEM4);
  cvt_f32_bf16<<<2048, 256, 0, stream>>>(Kf, Kb, NELEM4);
  cvt_f32_bf16<<<2048, 256, 0, stream>>>(Vf, Vb, NELEM4);
  cvt_f32_bf16<<<1024, 256, 0, stream>>>(WQw, Wqb, WELEM4);
  cvt_f32_bf16<<<1024, 256, 0, stream>>>(WKw, Wkb, WELEM4);
  cvt_f32_bf16<<<1024, 256, 0, stream>>>(WVw, Wvb, WELEM4);
  cvt_f32_bf16<<<1024, 256, 0, stream>>>(fcw, Wfb, WELEM4);

  dim3 gg(CD / GBN, (CB * CS) / GBM);
  gemm_nt<0><<<gg, 256, 0, stream>>>(Qb, Wqb, WQb, qhp, CB * CS, CD, CD);
  gemm_nt<0><<<gg, 256, 0, stream>>>(Kb, Wkb, WKb, khp, CB * CS, CD, CD);
  gemm_nt<1><<<gg, 256, 0, stream>>>(Vb, Wvb, WVb, vTp, CB * CS, CD, CD);

  dim3 ga(CS / 64, CH, CB);
  attn_fused<<<ga, 256, 0, stream>>>(qhp, khp, vTp, mask, attnw, apre);

  gemm_nt<2><<<gg, 256, 0, stream>>>(apre, Wfb, fcb, out0, CB * CS, CD, CD);
}